// Round 1
// baseline (762.829 us; speedup 1.0000x reference)
//
#include <hip/hip_runtime.h>
#include <stdint.h>
#include <stddef.h>

// ---------- types ----------
typedef __bf16 bf16_t;
typedef __attribute__((ext_vector_type(8))) __bf16 bf16x8;
typedef __attribute__((ext_vector_type(4))) float f32x4;
typedef __attribute__((ext_vector_type(4))) unsigned int u32x4;

#define LT 1024
#define LS 1024
#define DM 1024
#define NH 16
#define HD 64
#define FF 4096
#define BB 4

// ---------- weight transpose fp32[R,C] -> bf16[C,R] ----------
__global__ __launch_bounds__(256) void transpose_f2bf(
    const float* __restrict__ in, bf16_t* __restrict__ out, int R, int C)
{
    __shared__ float tile[32][33];
    int bx = blockIdx.x * 32;   // col origin in `in`
    int by = blockIdx.y * 32;   // row origin in `in`
    int tx = threadIdx.x, ty = threadIdx.y;   // (32, 8)
#pragma unroll
    for (int j = 0; j < 4; j++)
        tile[ty + j * 8][tx] = in[(size_t)(by + ty + j * 8) * C + bx + tx];
    __syncthreads();
#pragma unroll
    for (int j = 0; j < 4; j++)
        out[(size_t)(bx + ty + j * 8) * R + by + tx] = (bf16_t)tile[tx][ty + j * 8];
}

// ---------- fp32 -> bf16 convert ----------
__global__ __launch_bounds__(256) void f2bf_kernel(
    const float* __restrict__ in, bf16_t* __restrict__ out, size_t n)
{
    size_t i = ((size_t)blockIdx.x * 256 + threadIdx.x) * 4;
    if (i + 3 < n) {
        float4 v = *(const float4*)&in[i];
        out[i + 0] = (bf16_t)v.x;
        out[i + 1] = (bf16_t)v.y;
        out[i + 2] = (bf16_t)v.z;
        out[i + 3] = (bf16_t)v.w;
    }
}

// ---------- RMSNorm: fp32 row -> bf16 row ----------
__global__ __launch_bounds__(256) void rmsnorm_kernel(
    const float* __restrict__ x, const float* __restrict__ g,
    bf16_t* __restrict__ out)
{
    __shared__ float red[4];
    int row = blockIdx.x;
    int t = threadIdx.x;
    int lane = t & 63, w = t >> 6;
    const float* xr = x + (size_t)row * DM;
    float4 v = *(const float4*)&xr[t * 4];
    float ss = v.x * v.x + v.y * v.y + v.z * v.z + v.w * v.w;
#pragma unroll
    for (int off = 32; off > 0; off >>= 1) ss += __shfl_down(ss, off, 64);
    if (lane == 0) red[w] = ss;
    __syncthreads();
    float tot = red[0] + red[1] + red[2] + red[3];
    float inv = rsqrtf(tot * (1.0f / DM) + 1e-6f);
    float4 gv = *(const float4*)&g[t * 4];
    bf16_t* o = out + (size_t)row * DM + t * 4;
    o[0] = (bf16_t)(v.x * inv * gv.x);
    o[1] = (bf16_t)(v.y * inv * gv.y);
    o[2] = (bf16_t)(v.z * inv * gv.z);
    o[3] = (bf16_t)(v.w * inv * gv.w);
}

// ---------- GEMM C[M,N] = A[M,K] * Bt[N,K]^T  (bf16 in, fp32 acc) ----------
// epilogue modes
#define EP_Q 0      // bf16 head layout [B,H,LT,HD] -> outB
#define EP_KOUT 1   // fp32 head layout -> outF; bf16 head layout -> outB
#define EP_VOUT 2   // fp32 head layout -> outF; bf16 transposed [B,H,HD,LT] -> outB
#define EP_RES 3    // fp32 row-major + residual -> outF
#define EP_RELU 4   // bf16 row-major relu -> outB

template <int EP>
__global__ __launch_bounds__(256) void gemm_bt(
    const bf16_t* __restrict__ A, const bf16_t* __restrict__ Bt,
    int M, int N, int K,
    float* __restrict__ outF, const float* __restrict__ res,
    bf16_t* __restrict__ outB)
{
    __shared__ bf16_t lA[128 * 64];
    __shared__ bf16_t lB[128 * 64];
    const int t = threadIdx.x;
    const int lane = t & 63, w = t >> 6;
    const int quad = lane >> 4, l15 = lane & 15;
    const int m0 = blockIdx.x * 128, n0 = blockIdx.y * 128;
    const int wr = w >> 1, wc = w & 1;

    f32x4 acc[4][4] = {};

    for (int k0 = 0; k0 < K; k0 += 64) {
        __syncthreads();
#pragma unroll
        for (int i = 0; i < 4; i++) {
            int c = t + i * 256;            // 0..1023 chunks of 8 bf16
            int row = c >> 3, col = (c & 7) << 3;
            *(u32x4*)&lA[row * 64 + col] =
                *(const u32x4*)&A[(size_t)(m0 + row) * K + k0 + col];
            *(u32x4*)&lB[row * 64 + col] =
                *(const u32x4*)&Bt[(size_t)(n0 + row) * K + k0 + col];
        }
        __syncthreads();
#pragma unroll
        for (int s = 0; s < 2; s++) {
            bf16x8 af[4], bfr[4];
#pragma unroll
            for (int mt = 0; mt < 4; mt++)
                af[mt] = *(const bf16x8*)&lA[(wr * 64 + mt * 16 + l15) * 64 + s * 32 + quad * 8];
#pragma unroll
            for (int nt = 0; nt < 4; nt++)
                bfr[nt] = *(const bf16x8*)&lB[(wc * 64 + nt * 16 + l15) * 64 + s * 32 + quad * 8];
#pragma unroll
            for (int mt = 0; mt < 4; mt++)
#pragma unroll
                for (int nt = 0; nt < 4; nt++)
                    acc[mt][nt] = __builtin_amdgcn_mfma_f32_16x16x32_bf16(
                        af[mt], bfr[nt], acc[mt][nt], 0, 0, 0);
        }
    }

#pragma unroll
    for (int mt = 0; mt < 4; mt++) {
#pragma unroll
        for (int nt = 0; nt < 4; nt++) {
#pragma unroll
            for (int r = 0; r < 4; r++) {
                int row = m0 + wr * 64 + mt * 16 + quad * 4 + r;
                int col = n0 + wc * 64 + nt * 16 + l15;
                float v = acc[mt][nt][r];
                if constexpr (EP == EP_RES) {
                    outF[(size_t)row * N + col] = v + res[(size_t)row * N + col];
                } else if constexpr (EP == EP_RELU) {
                    outB[(size_t)row * N + col] = (bf16_t)fmaxf(v, 0.0f);
                } else {
                    int b = row >> 10, tp = row & 1023;   // row = b*LT + t
                    int h = col >> 6, d = col & 63;       // col = h*HD + d
                    size_t hb = ((size_t)(b * NH + h)) << 16; // * LT*HD
                    if constexpr (EP == EP_Q) {
                        outB[hb + (size_t)tp * HD + d] = (bf16_t)v;
                    } else if constexpr (EP == EP_KOUT) {
                        outF[hb + (size_t)tp * HD + d] = v;
                        outB[hb + (size_t)tp * HD + d] = (bf16_t)v;
                    } else { // EP_VOUT
                        outF[hb + (size_t)tp * HD + d] = v;
                        outB[hb + (size_t)d * LT + tp] = (bf16_t)v; // V^T [HD,L]
                    }
                }
            }
        }
    }
}

// ---------- flash attention ----------
// Q: [BH, L, 64] bf16, K: [BH, LS, 64] bf16, Vt: [BH, 64, LS] bf16
// bias (if !CAUSAL): fp32 [H, LT, LS]; out O: [B, LT, H*64] bf16
template <bool CAUSAL>
__global__ __launch_bounds__(256) void flash_attn(
    const bf16_t* __restrict__ Q, const bf16_t* __restrict__ Kb,
    const bf16_t* __restrict__ Vt, const float* __restrict__ bias,
    bf16_t* __restrict__ O)
{
    __shared__ bf16_t lK[64 * 64];
    __shared__ bf16_t lV[64 * 64];
    __shared__ bf16_t lP[4][16 * 64];
    const int t = threadIdx.x;
    const int lane = t & 63, w = t >> 6;
    const int quad = lane >> 4, l15 = lane & 15;
    const int qt = blockIdx.x;
    const int bh = blockIdx.y;
    const int b = bh >> 4, h = bh & 15;
    const int q0 = qt * 64;

    const bf16_t* qbase = Q + (size_t)bh * LT * HD;
    const bf16_t* kbase = Kb + (size_t)bh * LS * HD;
    const bf16_t* vbase = Vt + (size_t)bh * HD * LS;

    bf16x8 qf[2];
    int qrow = q0 + w * 16 + l15;
#pragma unroll
    for (int s = 0; s < 2; s++)
        qf[s] = *(const bf16x8*)&qbase[(size_t)qrow * HD + s * 32 + quad * 8];

    f32x4 acc_o[4] = {};
    float m_i[4], l_i[4];
#pragma unroll
    for (int r = 0; r < 4; r++) { m_i[r] = -3.0e38f; l_i[r] = 0.0f; }

    const int nkt = CAUSAL ? (qt + 1) : (LS / 64);
    for (int kt = 0; kt < nkt; kt++) {
        const int kb = kt * 64;
        __syncthreads();
#pragma unroll
        for (int i = 0; i < 2; i++) {
            int c = t + i * 256;             // 512 chunks of 8 bf16
            int row = c >> 3, col = (c & 7) << 3;
            *(u32x4*)&lK[row * 64 + col] =
                *(const u32x4*)&kbase[(size_t)(kb + row) * HD + col];
            *(u32x4*)&lV[row * 64 + col] =
                *(const u32x4*)&vbase[(size_t)row * LS + kb + col];
        }
        __syncthreads();

        // S tile = Q K^T (16 q-rows x 64 cols per wave)
        f32x4 sacc[4];
#pragma unroll
        for (int nt = 0; nt < 4; nt++) {
            f32x4 sa = {};
#pragma unroll
            for (int s = 0; s < 2; s++) {
                bf16x8 kf = *(const bf16x8*)&lK[(nt * 16 + l15) * 64 + s * 32 + quad * 8];
                sa = __builtin_amdgcn_mfma_f32_16x16x32_bf16(qf[s], kf, sa, 0, 0, 0);
            }
            sacc[nt] = sa;
        }

        float sval[4][4];
        float tmax[4];
#pragma unroll
        for (int r = 0; r < 4; r++) tmax[r] = -3.0e38f;
#pragma unroll
        for (int nt = 0; nt < 4; nt++) {
            int col = kb + nt * 16 + l15;
#pragma unroll
            for (int r = 0; r < 4; r++) {
                int row = q0 + w * 16 + quad * 4 + r;
                float v = sacc[nt][r] * 0.125f;
                if constexpr (CAUSAL) {
                    if (col > row) v = -1e9f;
                } else {
                    v += bias[((size_t)(h * LT + row)) * LS + col];
                }
                sval[nt][r] = v;
                tmax[r] = fmaxf(tmax[r], v);
            }
        }
#pragma unroll
        for (int r = 0; r < 4; r++) {
            float v = tmax[r];
            v = fmaxf(v, __shfl_xor(v, 1, 64));
            v = fmaxf(v, __shfl_xor(v, 2, 64));
            v = fmaxf(v, __shfl_xor(v, 4, 64));
            v = fmaxf(v, __shfl_xor(v, 8, 64));
            tmax[r] = v;
        }
        float alpha[4], rsum[4];
#pragma unroll
        for (int r = 0; r < 4; r++) {
            float mn = fmaxf(m_i[r], tmax[r]);
            alpha[r] = __expf(m_i[r] - mn);
            m_i[r] = mn;
            rsum[r] = 0.0f;
        }
#pragma unroll
        for (int nt = 0; nt < 4; nt++) {
#pragma unroll
            for (int r = 0; r < 4; r++) {
                float p = __expf(sval[nt][r] - m_i[r]);
                rsum[r] += p;
                lP[w][(quad * 4 + r) * 64 + nt * 16 + l15] = (bf16_t)p;
            }
        }
#pragma unroll
        for (int r = 0; r < 4; r++) {
            float v = rsum[r];
            v += __shfl_xor(v, 1, 64);
            v += __shfl_xor(v, 2, 64);
            v += __shfl_xor(v, 4, 64);
            v += __shfl_xor(v, 8, 64);
            l_i[r] = l_i[r] * alpha[r] + v;
        }
#pragma unroll
        for (int dt = 0; dt < 4; dt++)
#pragma unroll
            for (int r = 0; r < 4; r++)
                acc_o[dt][r] *= alpha[r];

        // O += P V  (P via LDS round-trip into A-layout)
#pragma unroll
        for (int s = 0; s < 2; s++) {
            bf16x8 pf = *(const bf16x8*)&lP[w][l15 * 64 + s * 32 + quad * 8];
#pragma unroll
            for (int dt = 0; dt < 4; dt++) {
                bf16x8 vf = *(const bf16x8*)&lV[(dt * 16 + l15) * 64 + s * 32 + quad * 8];
                acc_o[dt] = __builtin_amdgcn_mfma_f32_16x16x32_bf16(pf, vf, acc_o[dt], 0, 0, 0);
            }
        }
    }

#pragma unroll
    for (int dt = 0; dt < 4; dt++) {
#pragma unroll
        for (int r = 0; r < 4; r++) {
            int row = q0 + w * 16 + quad * 4 + r;
            int col = h * HD + dt * 16 + l15;
            float v = acc_o[dt][r] / l_i[r];
            O[((size_t)(b * LT + row)) * DM + col] = (bf16_t)v;
        }
    }
}

// ---------- host ----------
extern "C" void kernel_launch(void* const* d_in, const int* in_sizes, int n_in,
                              void* d_out, int out_size, void* d_ws, size_t ws_size,
                              hipStream_t stream)
{
    (void)in_sizes; (void)n_in; (void)out_size; (void)ws_size;
    const float* x    = (const float*)d_in[0];
    const float* mem  = (const float*)d_in[1];
    const float* pemb = (const float*)d_in[2];
    // d_in[3] = causal_mask (handled analytically)
    const float* g_sa = (const float*)d_in[4];
    const float* wq_s = (const float*)d_in[5];
    const float* wk_s = (const float*)d_in[6];
    const float* wv_s = (const float*)d_in[7];
    const float* wo_s = (const float*)d_in[8];
    const float* g_ca = (const float*)d_in[9];
    const float* wq_c = (const float*)d_in[10];
    const float* wk_c = (const float*)d_in[11];
    const float* wv_c = (const float*)d_in[12];
    const float* wo_c = (const float*)d_in[13];
    const float* g_m  = (const float*)d_in[14];
    const float* w1   = (const float*)d_in[15];
    const float* w2   = (const float*)d_in[16];
    float* out = (float*)d_out;

    const size_t OFF_KS = 4u * 1024 * 1024;
    const size_t OFF_VS = 8u * 1024 * 1024;
    const size_t OFF_KC = 12u * 1024 * 1024;
    const size_t OFF_VC = 16u * 1024 * 1024;

    char* ws = (char*)d_ws;
    const size_t MB = 1024 * 1024;
    bf16_t* wqTs = (bf16_t*)(ws + 0 * MB);
    bf16_t* wkTs = (bf16_t*)(ws + 2 * MB);
    bf16_t* wvTs = (bf16_t*)(ws + 4 * MB);
    bf16_t* woTs = (bf16_t*)(ws + 6 * MB);
    bf16_t* wqTc = (bf16_t*)(ws + 8 * MB);
    bf16_t* wkTc = (bf16_t*)(ws + 10 * MB);
    bf16_t* wvTc = (bf16_t*)(ws + 12 * MB);
    bf16_t* woTc = (bf16_t*)(ws + 14 * MB);
    bf16_t* w1T  = (bf16_t*)(ws + 16 * MB);   // [4096,1024]
    bf16_t* w2T  = (bf16_t*)(ws + 24 * MB);   // [1024,4096]
    bf16_t* membf = (bf16_t*)(ws + 32 * MB);  // [4096,1024]
    bf16_t* hbuf  = (bf16_t*)(ws + 40 * MB);  // [4096,1024] (h, h2, h3)
    bf16_t* qbuf  = (bf16_t*)(ws + 48 * MB);  // [B,H,LT,HD]
    bf16_t* kbuf  = (bf16_t*)(ws + 56 * MB);  // [B,H,LS,HD]
    bf16_t* vTbuf = (bf16_t*)(ws + 64 * MB);  // [B,H,HD,LS]
    bf16_t* Obuf  = (bf16_t*)(ws + 72 * MB);  // [B,LT,D]
    float*  attn_x  = (float*)(ws + 80 * MB); // [4096,1024] fp32
    float*  cross_x = (float*)(ws + 96 * MB); // [4096,1024] fp32
    bf16_t* ffnmid  = (bf16_t*)(ws + 112 * MB); // [4096,4096]

    dim3 tb(32, 8);
    transpose_f2bf<<<dim3(32, 32), tb, 0, stream>>>(wq_s, wqTs, DM, DM);
    transpose_f2bf<<<dim3(32, 32), tb, 0, stream>>>(wk_s, wkTs, DM, DM);
    transpose_f2bf<<<dim3(32, 32), tb, 0, stream>>>(wv_s, wvTs, DM, DM);
    transpose_f2bf<<<dim3(32, 32), tb, 0, stream>>>(wo_s, woTs, DM, DM);
    transpose_f2bf<<<dim3(32, 32), tb, 0, stream>>>(wq_c, wqTc, DM, DM);
    transpose_f2bf<<<dim3(32, 32), tb, 0, stream>>>(wk_c, wkTc, DM, DM);
    transpose_f2bf<<<dim3(32, 32), tb, 0, stream>>>(wv_c, wvTc, DM, DM);
    transpose_f2bf<<<dim3(32, 32), tb, 0, stream>>>(wo_c, woTc, DM, DM);
    transpose_f2bf<<<dim3(128, 32), tb, 0, stream>>>(w1, w1T, DM, FF);
    transpose_f2bf<<<dim3(32, 128), tb, 0, stream>>>(w2, w2T, FF, DM);

    f2bf_kernel<<<4096, 256, 0, stream>>>(mem, membf, (size_t)BB * LS * DM);

    dim3 g8(32, 8);    // M=4096 / 128, N=1024 / 128
    dim3 g32(32, 32);  // N=4096

    // ---- self-attention block ----
    rmsnorm_kernel<<<BB * LT, 256, 0, stream>>>(x, g_sa, hbuf);
    gemm_bt<EP_Q><<<g8, 256, 0, stream>>>(hbuf, wqTs, 4096, 1024, 1024, nullptr, nullptr, qbuf);
    gemm_bt<EP_KOUT><<<g8, 256, 0, stream>>>(hbuf, wkTs, 4096, 1024, 1024, out + OFF_KS, nullptr, kbuf);
    gemm_bt<EP_VOUT><<<g8, 256, 0, stream>>>(hbuf, wvTs, 4096, 1024, 1024, out + OFF_VS, nullptr, vTbuf);
    flash_attn<true><<<dim3(16, 64), 256, 0, stream>>>(qbuf, kbuf, vTbuf, nullptr, Obuf);
    gemm_bt<EP_RES><<<g8, 256, 0, stream>>>(Obuf, woTs, 4096, 1024, 1024, attn_x, x, nullptr);

    // ---- cross-attention block ----
    rmsnorm_kernel<<<BB * LT, 256, 0, stream>>>(attn_x, g_ca, hbuf);
    gemm_bt<EP_Q><<<g8, 256, 0, stream>>>(hbuf, wqTc, 4096, 1024, 1024, nullptr, nullptr, qbuf);
    gemm_bt<EP_KOUT><<<g8, 256, 0, stream>>>(membf, wkTc, 4096, 1024, 1024, out + OFF_KC, nullptr, kbuf);
    gemm_bt<EP_VOUT><<<g8, 256, 0, stream>>>(membf, wvTc, 4096, 1024, 1024, out + OFF_VC, nullptr, vTbuf);
    flash_attn<false><<<dim3(16, 64), 256, 0, stream>>>(qbuf, kbuf, vTbuf, pemb, Obuf);
    gemm_bt<EP_RES><<<g8, 256, 0, stream>>>(Obuf, woTc, 4096, 1024, 1024, cross_x, attn_x, nullptr);

    // ---- FFN block ----
    rmsnorm_kernel<<<BB * LT, 256, 0, stream>>>(cross_x, g_m, hbuf);
    gemm_bt<EP_RELU><<<g32, 256, 0, stream>>>(hbuf, w1T, 4096, 4096, 1024, nullptr, nullptr, ffnmid);
    gemm_bt<EP_RES><<<g8, 256, 0, stream>>>(ffnmid, w2T, 4096, 1024, 4096, out, cross_x, nullptr);
}

// Round 2
// 722.623 us; speedup vs baseline: 1.0556x; 1.0556x over previous
//
#include <hip/hip_runtime.h>
#include <stdint.h>
#include <stddef.h>

// ---------- types ----------
typedef __bf16 bf16_t;
typedef __attribute__((ext_vector_type(8))) __bf16 bf16x8;
typedef __attribute__((ext_vector_type(4))) float f32x4;

#define LT 1024
#define LS 1024
#define DM 1024
#define NH 16
#define HD 64
#define FF 4096
#define BB 4

// async global->LDS, 16B per lane; LDS deposit = wave-uniform base + lane*16
__device__ __forceinline__ void gld_lds16(const bf16_t* g, bf16_t* l) {
    __builtin_amdgcn_global_load_lds(
        (const __attribute__((address_space(1))) void*)g,
        (__attribute__((address_space(3))) void*)l, 16, 0, 0);
}

// ---------- weight transpose fp32[R,C] -> bf16[C,R] ----------
__global__ __launch_bounds__(256) void transpose_f2bf(
    const float* __restrict__ in, bf16_t* __restrict__ out, int R, int C)
{
    __shared__ float tile[32][33];
    int bx = blockIdx.x * 32;
    int by = blockIdx.y * 32;
    int tx = threadIdx.x, ty = threadIdx.y;   // (32, 8)
#pragma unroll
    for (int j = 0; j < 4; j++)
        tile[ty + j * 8][tx] = in[(size_t)(by + ty + j * 8) * C + bx + tx];
    __syncthreads();
#pragma unroll
    for (int j = 0; j < 4; j++)
        out[(size_t)(bx + ty + j * 8) * R + by + tx] = (bf16_t)tile[tx][ty + j * 8];
}

// ---------- fp32 -> bf16 convert ----------
__global__ __launch_bounds__(256) void f2bf_kernel(
    const float* __restrict__ in, bf16_t* __restrict__ out, size_t n)
{
    size_t i = ((size_t)blockIdx.x * 256 + threadIdx.x) * 4;
    if (i + 3 < n) {
        float4 v = *(const float4*)&in[i];
        out[i + 0] = (bf16_t)v.x;
        out[i + 1] = (bf16_t)v.y;
        out[i + 2] = (bf16_t)v.z;
        out[i + 3] = (bf16_t)v.w;
    }
}

// ---------- RMSNorm: fp32 row -> bf16 row ----------
__global__ __launch_bounds__(256) void rmsnorm_kernel(
    const float* __restrict__ x, const float* __restrict__ g,
    bf16_t* __restrict__ out)
{
    __shared__ float red[4];
    int row = blockIdx.x;
    int t = threadIdx.x;
    int lane = t & 63, w = t >> 6;
    const float* xr = x + (size_t)row * DM;
    float4 v = *(const float4*)&xr[t * 4];
    float ss = v.x * v.x + v.y * v.y + v.z * v.z + v.w * v.w;
#pragma unroll
    for (int off = 32; off > 0; off >>= 1) ss += __shfl_down(ss, off, 64);
    if (lane == 0) red[w] = ss;
    __syncthreads();
    float tot = red[0] + red[1] + red[2] + red[3];
    float inv = rsqrtf(tot * (1.0f / DM) + 1e-6f);
    float4 gv = *(const float4*)&g[t * 4];
    bf16_t* o = out + (size_t)row * DM + t * 4;
    o[0] = (bf16_t)(v.x * inv * gv.x);
    o[1] = (bf16_t)(v.y * inv * gv.y);
    o[2] = (bf16_t)(v.z * inv * gv.z);
    o[3] = (bf16_t)(v.w * inv * gv.w);
}

// ---------- GEMM C[M,N] = A[M,K] * Bt[N,K]^T  (bf16 in, fp32 acc) ----------
// EP_QKV: route by column section (Q/K/V head layouts)
// EP_RES: atomicAdd fp32 into pre-initialized (residual) buffer
// EP_RELU: bf16 row-major relu
#define EP_QKV 0
#define EP_RES 1
#define EP_RELU 2

template <int EP, int KSPLIT>
__global__ __launch_bounds__(256) void gemm_bt(
    const bf16_t* __restrict__ A, const bf16_t* __restrict__ Bt,
    int N, int K, int sec_base,
    float* __restrict__ outF, bf16_t* __restrict__ outB,
    bf16_t* __restrict__ qb,
    float* __restrict__ kF, bf16_t* __restrict__ kB,
    float* __restrict__ vF, bf16_t* __restrict__ vB)
{
    __shared__ bf16_t lA[128 * 64];
    __shared__ bf16_t lB[128 * 64];
    const int t = threadIdx.x;
    const int lane = t & 63, w = t >> 6;
    const int quad = lane >> 4, l15 = lane & 15;
    const int m0 = blockIdx.x * 128, n0 = blockIdx.y * 128;
    const int wr = w >> 1, wc = w & 1;
    const int Kc = K / KSPLIT;
    const int kBeg = blockIdx.z * Kc, kEnd = kBeg + Kc;

    f32x4 acc[4][4] = {};

    for (int k0 = kBeg; k0 < kEnd; k0 += 64) {
        __syncthreads();
#pragma unroll
        for (int i = 0; i < 4; i++) {
            int p = i * 256 + t;              // granule index 0..1023
            int row = p >> 3;
            int g = (p & 7) ^ (row & 7);      // global granule so deposit lands swizzled
            gld_lds16(&A[(size_t)(m0 + row) * K + k0 + g * 8], &lA[p * 8]);
            gld_lds16(&Bt[(size_t)(n0 + row) * K + k0 + g * 8], &lB[p * 8]);
        }
        __syncthreads();
#pragma unroll
        for (int s = 0; s < 2; s++) {
            bf16x8 af[4], bfr[4];
#pragma unroll
            for (int mt = 0; mt < 4; mt++) {
                int r = wr * 64 + mt * 16 + l15;
                af[mt] = *(const bf16x8*)&lA[((r << 3) + ((s * 4 + quad) ^ (r & 7))) << 3];
            }
#pragma unroll
            for (int nt = 0; nt < 4; nt++) {
                int r = wc * 64 + nt * 16 + l15;
                bfr[nt] = *(const bf16x8*)&lB[((r << 3) + ((s * 4 + quad) ^ (r & 7))) << 3];
            }
#pragma unroll
            for (int mt = 0; mt < 4; mt++)
#pragma unroll
                for (int nt = 0; nt < 4; nt++)
                    acc[mt][nt] = __builtin_amdgcn_mfma_f32_16x16x32_bf16(
                        af[mt], bfr[nt], acc[mt][nt], 0, 0, 0);
        }
    }

#pragma unroll
    for (int mt = 0; mt < 4; mt++) {
#pragma unroll
        for (int nt = 0; nt < 4; nt++) {
#pragma unroll
            for (int r = 0; r < 4; r++) {
                int row = m0 + wr * 64 + mt * 16 + quad * 4 + r;
                int col = n0 + wc * 64 + nt * 16 + l15;
                float v = acc[mt][nt][r];
                if constexpr (EP == EP_RES) {
                    atomicAdd(&outF[(size_t)row * N + col], v);
                } else if constexpr (EP == EP_RELU) {
                    outB[(size_t)row * N + col] = (bf16_t)fmaxf(v, 0.0f);
                } else {
                    int b = row >> 10, tp = row & 1023;
                    int c10 = col & 1023;
                    int sec = (col >> 10) + sec_base;
                    int h = c10 >> 6, d = c10 & 63;
                    size_t hb = ((size_t)(b * NH + h)) << 16;
                    if (sec == 0) {
                        qb[hb + (size_t)tp * HD + d] = (bf16_t)v;
                    } else if (sec == 1) {
                        kF[hb + (size_t)tp * HD + d] = v;
                        kB[hb + (size_t)tp * HD + d] = (bf16_t)v;
                    } else {
                        vF[hb + (size_t)tp * HD + d] = v;
                        vB[hb + (size_t)d * LT + tp] = (bf16_t)v;   // V^T [HD,L]
                    }
                }
            }
        }
    }
}

// ---------- flash attention ----------
// Q: [BH, L, 64] bf16, K: [BH, LS, 64] bf16, Vt: [BH, 64, LS] bf16
// bias (if !CAUSAL): fp32 [H, LT, LS]; out O: [B, LT, H*64] bf16
template <bool CAUSAL>
__global__ __launch_bounds__(256) void flash_attn(
    const bf16_t* __restrict__ Q, const bf16_t* __restrict__ Kb,
    const bf16_t* __restrict__ Vt, const float* __restrict__ bias,
    bf16_t* __restrict__ O)
{
    __shared__ bf16_t lK[64 * 64];
    __shared__ bf16_t lV[64 * 64];
    __shared__ bf16_t lP[4][16 * 64];
    const int t = threadIdx.x;
    const int lane = t & 63, w = t >> 6;
    const int quad = lane >> 4, l15 = lane & 15;
    const int qt = blockIdx.x;
    const int bh = blockIdx.y;
    const int b = bh >> 4, h = bh & 15;
    const int q0 = qt * 64;

    const bf16_t* qbase = Q + (size_t)bh * LT * HD;
    const bf16_t* kbase = Kb + (size_t)bh * LS * HD;
    const bf16_t* vbase = Vt + (size_t)bh * HD * LS;

    bf16x8 qf[2];
    int qrow = q0 + w * 16 + l15;
#pragma unroll
    for (int s = 0; s < 2; s++)
        qf[s] = *(const bf16x8*)&qbase[(size_t)qrow * HD + s * 32 + quad * 8];

    f32x4 acc_o[4] = {};
    float m_i[4], l_i[4];
#pragma unroll
    for (int r = 0; r < 4; r++) { m_i[r] = -3.0e38f; l_i[r] = 0.0f; }

    const int nkt = CAUSAL ? (qt + 1) : (LS / 64);
    for (int kt = 0; kt < nkt; kt++) {
        const int kb = kt * 64;
        __syncthreads();
#pragma unroll
        for (int i = 0; i < 2; i++) {
            int p = i * 256 + t;              // granule 0..511
            int row = p >> 3;
            int g = (p & 7) ^ (row & 7);
            gld_lds16(&kbase[(size_t)(kb + row) * HD + g * 8], &lK[p * 8]);
            gld_lds16(&vbase[(size_t)row * LS + kb + g * 8], &lV[p * 8]);
        }
        __syncthreads();

        // S tile = Q K^T (16 q-rows x 64 cols per wave)
        f32x4 sacc[4];
#pragma unroll
        for (int nt = 0; nt < 4; nt++) {
            f32x4 sa = {};
#pragma unroll
            for (int s = 0; s < 2; s++) {
                int r = nt * 16 + l15;
                bf16x8 kf = *(const bf16x8*)&lK[((r << 3) + ((s * 4 + quad) ^ (r & 7))) << 3];
                sa = __builtin_amdgcn_mfma_f32_16x16x32_bf16(qf[s], kf, sa, 0, 0, 0);
            }
            sacc[nt] = sa;
        }

        float sval[4][4];
        float tmax[4];
#pragma unroll
        for (int r = 0; r < 4; r++) tmax[r] = -3.0e38f;
#pragma unroll
        for (int nt = 0; nt < 4; nt++) {
            int col = kb + nt * 16 + l15;
#pragma unroll
            for (int r = 0; r < 4; r++) {
                int row = q0 + w * 16 + quad * 4 + r;
                float v = sacc[nt][r] * 0.125f;
                if constexpr (CAUSAL) {
                    if (col > row) v = -1e9f;
                } else {
                    v += bias[((size_t)(h * LT + row)) * LS + col];
                }
                sval[nt][r] = v;
                tmax[r] = fmaxf(tmax[r], v);
            }
        }
#pragma unroll
        for (int r = 0; r < 4; r++) {
            float v = tmax[r];
            v = fmaxf(v, __shfl_xor(v, 1, 64));
            v = fmaxf(v, __shfl_xor(v, 2, 64));
            v = fmaxf(v, __shfl_xor(v, 4, 64));
            v = fmaxf(v, __shfl_xor(v, 8, 64));
            tmax[r] = v;
        }
        float alpha[4], rsum[4];
#pragma unroll
        for (int r = 0; r < 4; r++) {
            float mn = fmaxf(m_i[r], tmax[r]);
            alpha[r] = __expf(m_i[r] - mn);
            m_i[r] = mn;
            rsum[r] = 0.0f;
        }
#pragma unroll
        for (int nt = 0; nt < 4; nt++) {
#pragma unroll
            for (int r = 0; r < 4; r++) {
                float p = __expf(sval[nt][r] - m_i[r]);
                rsum[r] += p;
                int pr = quad * 4 + r;
                int gcol = nt * 2 + (l15 >> 3);
                lP[w][((pr << 3) + (gcol ^ (pr & 7))) * 8 + (l15 & 7)] = (bf16_t)p;
            }
        }
#pragma unroll
        for (int r = 0; r < 4; r++) {
            float v = rsum[r];
            v += __shfl_xor(v, 1, 64);
            v += __shfl_xor(v, 2, 64);
            v += __shfl_xor(v, 4, 64);
            v += __shfl_xor(v, 8, 64);
            l_i[r] = l_i[r] * alpha[r] + v;
        }
#pragma unroll
        for (int dt = 0; dt < 4; dt++)
#pragma unroll
            for (int r = 0; r < 4; r++)
                acc_o[dt][r] *= alpha[r];

        // O += P V  (P via wave-private LDS round-trip into A-layout)
#pragma unroll
        for (int s = 0; s < 2; s++) {
            bf16x8 pf = *(const bf16x8*)&lP[w][((l15 << 3) + ((s * 4 + quad) ^ (l15 & 7))) << 3];
#pragma unroll
            for (int dt = 0; dt < 4; dt++) {
                int r = dt * 16 + l15;
                bf16x8 vf = *(const bf16x8*)&lV[((r << 3) + ((s * 4 + quad) ^ (r & 7))) << 3];
                acc_o[dt] = __builtin_amdgcn_mfma_f32_16x16x32_bf16(pf, vf, acc_o[dt], 0, 0, 0);
            }
        }
    }

#pragma unroll
    for (int dt = 0; dt < 4; dt++) {
#pragma unroll
        for (int r = 0; r < 4; r++) {
            int row = q0 + w * 16 + quad * 4 + r;
            int col = h * HD + dt * 16 + l15;
            float v = acc_o[dt][r] / l_i[r];
            O[((size_t)(b * LT + row)) * DM + col] = (bf16_t)v;
        }
    }
}

// ---------- host ----------
extern "C" void kernel_launch(void* const* d_in, const int* in_sizes, int n_in,
                              void* d_out, int out_size, void* d_ws, size_t ws_size,
                              hipStream_t stream)
{
    (void)in_sizes; (void)n_in; (void)out_size; (void)ws_size;
    const float* x    = (const float*)d_in[0];
    const float* mem  = (const float*)d_in[1];
    const float* pemb = (const float*)d_in[2];
    const float* g_sa = (const float*)d_in[4];
    const float* wq_s = (const float*)d_in[5];
    const float* wk_s = (const float*)d_in[6];
    const float* wv_s = (const float*)d_in[7];
    const float* wo_s = (const float*)d_in[8];
    const float* g_ca = (const float*)d_in[9];
    const float* wq_c = (const float*)d_in[10];
    const float* wk_c = (const float*)d_in[11];
    const float* wv_c = (const float*)d_in[12];
    const float* wo_c = (const float*)d_in[13];
    const float* g_m  = (const float*)d_in[14];
    const float* w1   = (const float*)d_in[15];
    const float* w2   = (const float*)d_in[16];
    float* out = (float*)d_out;

    const size_t OFF_KS = 4u * 1024 * 1024;
    const size_t OFF_VS = 8u * 1024 * 1024;
    const size_t OFF_KC = 12u * 1024 * 1024;
    const size_t OFF_VC = 16u * 1024 * 1024;

    char* ws = (char*)d_ws;
    const size_t MB = 1024 * 1024;
    bf16_t* wqkvTs = (bf16_t*)(ws + 0 * MB);   // [3072,1024]
    bf16_t* woTs   = (bf16_t*)(ws + 6 * MB);
    bf16_t* wqTc   = (bf16_t*)(ws + 8 * MB);
    bf16_t* wkvTc  = (bf16_t*)(ws + 10 * MB);  // [2048,1024]
    bf16_t* woTc   = (bf16_t*)(ws + 14 * MB);
    bf16_t* w1T    = (bf16_t*)(ws + 16 * MB);  // [4096,1024]
    bf16_t* w2T    = (bf16_t*)(ws + 24 * MB);  // [1024,4096]
    bf16_t* membf  = (bf16_t*)(ws + 32 * MB);  // [4096,1024]
    bf16_t* hbuf   = (bf16_t*)(ws + 40 * MB);  // [4096,1024]
    bf16_t* qbuf   = (bf16_t*)(ws + 48 * MB);  // [B,H,LT,HD]
    bf16_t* kbuf   = (bf16_t*)(ws + 56 * MB);  // [B,H,LS,HD]
    bf16_t* vTbuf  = (bf16_t*)(ws + 64 * MB);  // [B,H,HD,LS]
    bf16_t* Obuf   = (bf16_t*)(ws + 72 * MB);  // [B,LT,D]
    float*  attn_x  = (float*)(ws + 80 * MB);  // fp32 [4096,1024]
    float*  cross_x = (float*)(ws + 96 * MB);  // fp32 [4096,1024]
    bf16_t* ffnmid  = (bf16_t*)(ws + 112 * MB);// [4096,4096]

    dim3 tb(32, 8);
    transpose_f2bf<<<dim3(32, 32), tb, 0, stream>>>(wq_s, wqkvTs, DM, DM);
    transpose_f2bf<<<dim3(32, 32), tb, 0, stream>>>(wk_s, wqkvTs + 1024 * 1024, DM, DM);
    transpose_f2bf<<<dim3(32, 32), tb, 0, stream>>>(wv_s, wqkvTs + 2 * 1024 * 1024, DM, DM);
    transpose_f2bf<<<dim3(32, 32), tb, 0, stream>>>(wo_s, woTs, DM, DM);
    transpose_f2bf<<<dim3(32, 32), tb, 0, stream>>>(wq_c, wqTc, DM, DM);
    transpose_f2bf<<<dim3(32, 32), tb, 0, stream>>>(wk_c, wkvTc, DM, DM);
    transpose_f2bf<<<dim3(32, 32), tb, 0, stream>>>(wv_c, wkvTc + 1024 * 1024, DM, DM);
    transpose_f2bf<<<dim3(32, 32), tb, 0, stream>>>(wo_c, woTc, DM, DM);
    transpose_f2bf<<<dim3(128, 32), tb, 0, stream>>>(w1, w1T, DM, FF);
    transpose_f2bf<<<dim3(32, 128), tb, 0, stream>>>(w2, w2T, FF, DM);

    f2bf_kernel<<<4096, 256, 0, stream>>>(mem, membf, (size_t)BB * LS * DM);

    const size_t ROWB = (size_t)BB * LT * DM * sizeof(float);  // 16 MB

    // ---- self-attention block ----
    rmsnorm_kernel<<<BB * LT, 256, 0, stream>>>(x, g_sa, hbuf);
    gemm_bt<EP_QKV, 1><<<dim3(32, 24), 256, 0, stream>>>(
        hbuf, wqkvTs, 3072, 1024, 0, nullptr, nullptr,
        qbuf, out + OFF_KS, kbuf, out + OFF_VS, vTbuf);
    flash_attn<true><<<dim3(16, 64), 256, 0, stream>>>(qbuf, kbuf, vTbuf, nullptr, Obuf);
    hipMemcpyAsync(attn_x, x, ROWB, hipMemcpyDeviceToDevice, stream);
    gemm_bt<EP_RES, 1><<<dim3(32, 8), 256, 0, stream>>>(
        Obuf, woTs, 1024, 1024, 0, attn_x, nullptr,
        nullptr, nullptr, nullptr, nullptr, nullptr);

    // ---- cross-attention block ----
    rmsnorm_kernel<<<BB * LT, 256, 0, stream>>>(attn_x, g_ca, hbuf);
    gemm_bt<EP_QKV, 1><<<dim3(32, 8), 256, 0, stream>>>(
        hbuf, wqTc, 1024, 1024, 0, nullptr, nullptr,
        qbuf, nullptr, nullptr, nullptr, nullptr);
    gemm_bt<EP_QKV, 1><<<dim3(32, 16), 256, 0, stream>>>(
        membf, wkvTc, 2048, 1024, 1, nullptr, nullptr,
        nullptr, out + OFF_KC, kbuf, out + OFF_VC, vTbuf);
    flash_attn<false><<<dim3(16, 64), 256, 0, stream>>>(qbuf, kbuf, vTbuf, pemb, Obuf);
    hipMemcpyAsync(cross_x, attn_x, ROWB, hipMemcpyDeviceToDevice, stream);
    gemm_bt<EP_RES, 1><<<dim3(32, 8), 256, 0, stream>>>(
        Obuf, woTc, 1024, 1024, 0, cross_x, nullptr,
        nullptr, nullptr, nullptr, nullptr, nullptr);

    // ---- FFN block ----
    rmsnorm_kernel<<<BB * LT, 256, 0, stream>>>(cross_x, g_m, hbuf);
    gemm_bt<EP_RELU, 1><<<dim3(32, 32), 256, 0, stream>>>(
        hbuf, w1T, 4096, 1024, 0, nullptr, ffnmid,
        nullptr, nullptr, nullptr, nullptr, nullptr);
    hipMemcpyAsync(out, cross_x, ROWB, hipMemcpyDeviceToDevice, stream);
    gemm_bt<EP_RES, 4><<<dim3(32, 8, 4), 256, 0, stream>>>(
        ffnmid, w2T, 1024, 4096, 0, out, nullptr,
        nullptr, nullptr, nullptr, nullptr, nullptr);
}

// Round 3
// 654.922 us; speedup vs baseline: 1.1648x; 1.1034x over previous
//
#include <hip/hip_runtime.h>
#include <stdint.h>
#include <stddef.h>

// ---------- types ----------
typedef __bf16 bf16_t;
typedef __attribute__((ext_vector_type(8))) __bf16 bf16x8;
typedef __attribute__((ext_vector_type(4))) float f32x4;

#define LT 1024
#define LS 1024
#define DM 1024
#define NH 16
#define HD 64
#define FF 4096
#define BB 4

// async global->LDS, 16B per lane; LDS deposit = wave-uniform base + lane*16
__device__ __forceinline__ void gld_lds16(const bf16_t* g, bf16_t* l) {
    __builtin_amdgcn_global_load_lds(
        (const __attribute__((address_space(1))) void*)g,
        (__attribute__((address_space(3))) void*)l, 16, 0, 0);
}

// ---------- weight transpose fp32[R,C] -> bf16[C,R] ----------
__global__ __launch_bounds__(256) void transpose_f2bf(
    const float* __restrict__ in, bf16_t* __restrict__ out, int R, int C)
{
    __shared__ float tile[32][33];
    int bx = blockIdx.x * 32;
    int by = blockIdx.y * 32;
    int tx = threadIdx.x, ty = threadIdx.y;   // (32, 8)
#pragma unroll
    for (int j = 0; j < 4; j++)
        tile[ty + j * 8][tx] = in[(size_t)(by + ty + j * 8) * C + bx + tx];
    __syncthreads();
#pragma unroll
    for (int j = 0; j < 4; j++)
        out[(size_t)(bx + ty + j * 8) * R + by + tx] = (bf16_t)tile[tx][ty + j * 8];
}

// ---------- bf16 per-(b,h) transpose: [BH,L,HD] -> [BH,HD,L] ----------
__global__ __launch_bounds__(256) void transpose_bf(
    const bf16_t* __restrict__ in, bf16_t* __restrict__ out)
{
    __shared__ bf16_t tile[32][33];
    int bh = blockIdx.z;
    int r0 = blockIdx.x * 32;   // L dim
    int c0 = blockIdx.y * 32;   // HD dim
    const bf16_t* ib = in + (size_t)bh * LT * HD;
    bf16_t* ob = out + (size_t)bh * HD * LT;
    int tx = threadIdx.x, ty = threadIdx.y;
#pragma unroll
    for (int j = 0; j < 4; j++)
        tile[ty + j * 8][tx] = ib[(size_t)(r0 + ty + j * 8) * HD + c0 + tx];
    __syncthreads();
#pragma unroll
    for (int j = 0; j < 4; j++)
        ob[(size_t)(c0 + ty + j * 8) * LT + r0 + tx] = tile[tx][ty + j * 8];
}

// ---------- fp32 -> bf16 convert ----------
__global__ __launch_bounds__(256) void f2bf_kernel(
    const float* __restrict__ in, bf16_t* __restrict__ out, size_t n)
{
    size_t i = ((size_t)blockIdx.x * 256 + threadIdx.x) * 4;
    if (i + 3 < n) {
        float4 v = *(const float4*)&in[i];
        out[i + 0] = (bf16_t)v.x;
        out[i + 1] = (bf16_t)v.y;
        out[i + 2] = (bf16_t)v.z;
        out[i + 3] = (bf16_t)v.w;
    }
}

// ---------- split-K reduce + residual: out = p[0] + p[1] + res ----------
__global__ __launch_bounds__(256) void reduce2_res(
    const float* __restrict__ p, const float* __restrict__ res,
    float* __restrict__ out)
{
    const size_t MN = (size_t)BB * LT * DM;
    size_t i = ((size_t)blockIdx.x * 256 + threadIdx.x) * 4;
    float4 a = *(const float4*)&p[i];
    float4 b = *(const float4*)&p[i + MN];
    float4 r = *(const float4*)&res[i];
    float4 o;
    o.x = a.x + b.x + r.x; o.y = a.y + b.y + r.y;
    o.z = a.z + b.z + r.z; o.w = a.w + b.w + r.w;
    *(float4*)&out[i] = o;
}

// ---------- RMSNorm: fp32 row -> bf16 row ----------
__global__ __launch_bounds__(256) void rmsnorm_kernel(
    const float* __restrict__ x, const float* __restrict__ g,
    bf16_t* __restrict__ out)
{
    __shared__ float red[4];
    int row = blockIdx.x;
    int t = threadIdx.x;
    int lane = t & 63, w = t >> 6;
    const float* xr = x + (size_t)row * DM;
    float4 v = *(const float4*)&xr[t * 4];
    float ss = v.x * v.x + v.y * v.y + v.z * v.z + v.w * v.w;
#pragma unroll
    for (int off = 32; off > 0; off >>= 1) ss += __shfl_down(ss, off, 64);
    if (lane == 0) red[w] = ss;
    __syncthreads();
    float tot = red[0] + red[1] + red[2] + red[3];
    float inv = rsqrtf(tot * (1.0f / DM) + 1e-6f);
    float4 gv = *(const float4*)&g[t * 4];
    bf16_t* o = out + (size_t)row * DM + t * 4;
    o[0] = (bf16_t)(v.x * inv * gv.x);
    o[1] = (bf16_t)(v.y * inv * gv.y);
    o[2] = (bf16_t)(v.z * inv * gv.z);
    o[3] = (bf16_t)(v.w * inv * gv.w);
}

// ================= GEMM core (shared tile loop) =================
// acc += A[m0:m0+128, kBeg:kEnd] * Bt[n0:n0+128, kBeg:kEnd]^T
#define GEMM_BODY(Aptr, Btptr, Kstride, kBeg, kEnd)                              \
    for (int k0 = (kBeg); k0 < (kEnd); k0 += 64) {                               \
        __syncthreads();                                                         \
        _Pragma("unroll")                                                        \
        for (int i = 0; i < 4; i++) {                                            \
            int p = i * 256 + t;                                                 \
            int row = p >> 3;                                                    \
            int g = (p & 7) ^ (row & 7);                                         \
            gld_lds16(&(Aptr)[(size_t)(m0 + row) * (Kstride) + k0 + g * 8],      \
                      &lA[p * 8]);                                               \
            gld_lds16(&(Btptr)[(size_t)(n0 + row) * (Kstride) + k0 + g * 8],     \
                      &lB[p * 8]);                                               \
        }                                                                        \
        __syncthreads();                                                         \
        _Pragma("unroll")                                                        \
        for (int s = 0; s < 2; s++) {                                            \
            bf16x8 af[4], bfr[4];                                                \
            _Pragma("unroll")                                                    \
            for (int mt = 0; mt < 4; mt++) {                                     \
                int r = wr * 64 + mt * 16 + l15;                                 \
                af[mt] = *(const bf16x8*)&lA[((r << 3) + ((s * 4 + quad) ^ (r & 7))) << 3]; \
            }                                                                    \
            _Pragma("unroll")                                                    \
            for (int nt = 0; nt < 4; nt++) {                                     \
                int r = wc * 64 + nt * 16 + l15;                                 \
                bfr[nt] = *(const bf16x8*)&lB[((r << 3) + ((s * 4 + quad) ^ (r & 7))) << 3]; \
            }                                                                    \
            _Pragma("unroll")                                                    \
            for (int mt = 0; mt < 4; mt++)                                       \
                _Pragma("unroll")                                                \
                for (int nt = 0; nt < 4; nt++)                                   \
                    acc[mt][nt] = __builtin_amdgcn_mfma_f32_16x16x32_bf16(       \
                        af[mt], bfr[nt], acc[mt][nt], 0, 0, 0);                  \
        }                                                                        \
    }

// ---------- QKV projection GEMM (dual-source, head-layout epilogue) ----------
// grid.y < nb1 : A1*B1 (sections from secbase1); else A2*B2 (secbase2)
__global__ __launch_bounds__(256) void gemm_qkv(
    const bf16_t* __restrict__ A1, const bf16_t* __restrict__ B1, int nb1,
    const bf16_t* __restrict__ A2, const bf16_t* __restrict__ B2, int secbase2,
    bf16_t* __restrict__ qb,
    float* __restrict__ kF, bf16_t* __restrict__ kB,
    float* __restrict__ vF, bf16_t* __restrict__ vB)
{
    __shared__ bf16_t lA[128 * 64];
    __shared__ bf16_t lB[128 * 64];
    const int t = threadIdx.x;
    const int lane = t & 63, w = t >> 6;
    const int quad = lane >> 4, l15 = lane & 15;
    const int m0 = blockIdx.x * 128;
    const int wr = w >> 1, wc = w & 1;

    const bf16_t* A; const bf16_t* Bt; int n0, sec0;
    if ((int)blockIdx.y < nb1) { A = A1; Bt = B1; n0 = blockIdx.y * 128; sec0 = 0; }
    else { A = A2; Bt = B2; n0 = (blockIdx.y - nb1) * 128; sec0 = secbase2; }

    f32x4 acc[4][4] = {};
    GEMM_BODY(A, Bt, 1024, 0, 1024)

#pragma unroll
    for (int mt = 0; mt < 4; mt++) {
#pragma unroll
        for (int nt = 0; nt < 4; nt++) {
#pragma unroll
            for (int r = 0; r < 4; r++) {
                int row = m0 + wr * 64 + mt * 16 + quad * 4 + r;
                int col = n0 + wc * 64 + nt * 16 + l15;
                float v = acc[mt][nt][r];
                int b = row >> 10, tp = row & 1023;
                int sec = sec0 + (col >> 10);
                int c10 = col & 1023;
                int h = c10 >> 6, d = c10 & 63;
                size_t idx = (((size_t)(b * NH + h)) << 16) + (size_t)tp * HD + d;
                if (sec == 0) {
                    qb[idx] = (bf16_t)v;
                } else if (sec == 1) {
                    kF[idx] = v;
                    kB[idx] = (bf16_t)v;
                } else {
                    vF[idx] = v;
                    vB[idx] = (bf16_t)v;
                }
            }
        }
    }
}

// ---------- general GEMM: C[M,N] = A[M,K] * Bt[N,K]^T ----------
#define EP_RES 0    // fp32 store of (v + res)
#define EP_RELU 1   // bf16 relu store
#define EP_PART 2   // fp32 store to partial slice (split-K)

template <int EP, int KSPLIT>
__global__ __launch_bounds__(256) void gemm_bt(
    const bf16_t* __restrict__ A, const bf16_t* __restrict__ Bt,
    int N, int K,
    float* __restrict__ outF, const float* __restrict__ res,
    bf16_t* __restrict__ outB)
{
    __shared__ bf16_t lA[128 * 64];
    __shared__ bf16_t lB[128 * 64];
    const int t = threadIdx.x;
    const int lane = t & 63, w = t >> 6;
    const int quad = lane >> 4, l15 = lane & 15;
    const int m0 = blockIdx.x * 128, n0 = blockIdx.y * 128;
    const int wr = w >> 1, wc = w & 1;
    const int Kc = K / KSPLIT;
    const int kBeg = blockIdx.z * Kc;

    f32x4 acc[4][4] = {};
    GEMM_BODY(A, Bt, K, kBeg, kBeg + Kc)

    float* dst = outF;
    if constexpr (EP == EP_PART)
        dst = outF + (size_t)blockIdx.z * (size_t)gridDim.x * 128 * N;

#pragma unroll
    for (int mt = 0; mt < 4; mt++) {
#pragma unroll
        for (int nt = 0; nt < 4; nt++) {
#pragma unroll
            for (int r = 0; r < 4; r++) {
                int row = m0 + wr * 64 + mt * 16 + quad * 4 + r;
                int col = n0 + wc * 64 + nt * 16 + l15;
                float v = acc[mt][nt][r];
                if constexpr (EP == EP_RES) {
                    dst[(size_t)row * N + col] = v + res[(size_t)row * N + col];
                } else if constexpr (EP == EP_RELU) {
                    outB[(size_t)row * N + col] = (bf16_t)fmaxf(v, 0.0f);
                } else {
                    dst[(size_t)row * N + col] = v;
                }
            }
        }
    }
}

// ---------- flash attention ----------
template <bool CAUSAL>
__global__ __launch_bounds__(256) void flash_attn(
    const bf16_t* __restrict__ Q, const bf16_t* __restrict__ Kb,
    const bf16_t* __restrict__ Vt, const float* __restrict__ bias,
    bf16_t* __restrict__ O)
{
    __shared__ bf16_t lK[64 * 64];
    __shared__ bf16_t lV[64 * 64];
    __shared__ bf16_t lP[4][16 * 64];
    const int t = threadIdx.x;
    const int lane = t & 63, w = t >> 6;
    const int quad = lane >> 4, l15 = lane & 15;
    const int qt = blockIdx.x;
    const int bh = blockIdx.y;
    const int b = bh >> 4, h = bh & 15;
    const int q0 = qt * 64;

    const bf16_t* qbase = Q + (size_t)bh * LT * HD;
    const bf16_t* kbase = Kb + (size_t)bh * LS * HD;
    const bf16_t* vbase = Vt + (size_t)bh * HD * LS;

    bf16x8 qf[2];
    int qrow = q0 + w * 16 + l15;
#pragma unroll
    for (int s = 0; s < 2; s++)
        qf[s] = *(const bf16x8*)&qbase[(size_t)qrow * HD + s * 32 + quad * 8];

    f32x4 acc_o[4] = {};
    float m_i[4], l_i[4];
#pragma unroll
    for (int r = 0; r < 4; r++) { m_i[r] = -3.0e38f; l_i[r] = 0.0f; }

    const int nkt = CAUSAL ? (qt + 1) : (LS / 64);
    for (int kt = 0; kt < nkt; kt++) {
        const int kb = kt * 64;
        __syncthreads();
#pragma unroll
        for (int i = 0; i < 2; i++) {
            int p = i * 256 + t;
            int row = p >> 3;
            int g = (p & 7) ^ (row & 7);
            gld_lds16(&kbase[(size_t)(kb + row) * HD + g * 8], &lK[p * 8]);
            gld_lds16(&vbase[(size_t)row * LS + kb + g * 8], &lV[p * 8]);
        }
        __syncthreads();

        f32x4 sacc[4];
#pragma unroll
        for (int nt = 0; nt < 4; nt++) {
            f32x4 sa = {};
#pragma unroll
            for (int s = 0; s < 2; s++) {
                int r = nt * 16 + l15;
                bf16x8 kf = *(const bf16x8*)&lK[((r << 3) + ((s * 4 + quad) ^ (r & 7))) << 3];
                sa = __builtin_amdgcn_mfma_f32_16x16x32_bf16(qf[s], kf, sa, 0, 0, 0);
            }
            sacc[nt] = sa;
        }

        float sval[4][4];
        float tmax[4];
#pragma unroll
        for (int r = 0; r < 4; r++) tmax[r] = -3.0e38f;
#pragma unroll
        for (int nt = 0; nt < 4; nt++) {
            int col = kb + nt * 16 + l15;
#pragma unroll
            for (int r = 0; r < 4; r++) {
                int row = q0 + w * 16 + quad * 4 + r;
                float v = sacc[nt][r] * 0.125f;
                if constexpr (CAUSAL) {
                    if (col > row) v = -1e9f;
                } else {
                    v += bias[((size_t)(h * LT + row)) * LS + col];
                }
                sval[nt][r] = v;
                tmax[r] = fmaxf(tmax[r], v);
            }
        }
#pragma unroll
        for (int r = 0; r < 4; r++) {
            float v = tmax[r];
            v = fmaxf(v, __shfl_xor(v, 1, 64));
            v = fmaxf(v, __shfl_xor(v, 2, 64));
            v = fmaxf(v, __shfl_xor(v, 4, 64));
            v = fmaxf(v, __shfl_xor(v, 8, 64));
            tmax[r] = v;
        }
        float alpha[4], rsum[4];
#pragma unroll
        for (int r = 0; r < 4; r++) {
            float mn = fmaxf(m_i[r], tmax[r]);
            alpha[r] = __expf(m_i[r] - mn);
            m_i[r] = mn;
            rsum[r] = 0.0f;
        }
#pragma unroll
        for (int nt = 0; nt < 4; nt++) {
#pragma unroll
            for (int r = 0; r < 4; r++) {
                float p = __expf(sval[nt][r] - m_i[r]);
                rsum[r] += p;
                int pr = quad * 4 + r;
                int gcol = nt * 2 + (l15 >> 3);
                lP[w][((pr << 3) + (gcol ^ (pr & 7))) * 8 + (l15 & 7)] = (bf16_t)p;
            }
        }
#pragma unroll
        for (int r = 0; r < 4; r++) {
            float v = rsum[r];
            v += __shfl_xor(v, 1, 64);
            v += __shfl_xor(v, 2, 64);
            v += __shfl_xor(v, 4, 64);
            v += __shfl_xor(v, 8, 64);
            l_i[r] = l_i[r] * alpha[r] + v;
        }
#pragma unroll
        for (int dt = 0; dt < 4; dt++)
#pragma unroll
            for (int r = 0; r < 4; r++)
                acc_o[dt][r] *= alpha[r];

#pragma unroll
        for (int s = 0; s < 2; s++) {
            bf16x8 pf = *(const bf16x8*)&lP[w][((l15 << 3) + ((s * 4 + quad) ^ (l15 & 7))) << 3];
#pragma unroll
            for (int dt = 0; dt < 4; dt++) {
                int r = dt * 16 + l15;
                bf16x8 vf = *(const bf16x8*)&lV[((r << 3) + ((s * 4 + quad) ^ (r & 7))) << 3];
                acc_o[dt] = __builtin_amdgcn_mfma_f32_16x16x32_bf16(pf, vf, acc_o[dt], 0, 0, 0);
            }
        }
    }

#pragma unroll
    for (int dt = 0; dt < 4; dt++) {
#pragma unroll
        for (int r = 0; r < 4; r++) {
            int row = q0 + w * 16 + quad * 4 + r;
            int col = h * HD + dt * 16 + l15;
            float v = acc_o[dt][r] / l_i[r];
            O[((size_t)(b * LT + row)) * DM + col] = (bf16_t)v;
        }
    }
}

// ---------- host ----------
extern "C" void kernel_launch(void* const* d_in, const int* in_sizes, int n_in,
                              void* d_out, int out_size, void* d_ws, size_t ws_size,
                              hipStream_t stream)
{
    (void)in_sizes; (void)n_in; (void)out_size; (void)ws_size;
    const float* x    = (const float*)d_in[0];
    const float* mem  = (const float*)d_in[1];
    const float* pemb = (const float*)d_in[2];
    const float* g_sa = (const float*)d_in[4];
    const float* wq_s = (const float*)d_in[5];
    const float* wk_s = (const float*)d_in[6];
    const float* wv_s = (const float*)d_in[7];
    const float* wo_s = (const float*)d_in[8];
    const float* g_ca = (const float*)d_in[9];
    const float* wq_c = (const float*)d_in[10];
    const float* wk_c = (const float*)d_in[11];
    const float* wv_c = (const float*)d_in[12];
    const float* wo_c = (const float*)d_in[13];
    const float* g_m  = (const float*)d_in[14];
    const float* w1   = (const float*)d_in[15];
    const float* w2   = (const float*)d_in[16];
    float* out = (float*)d_out;

    const size_t OFF_KS = 4u * 1024 * 1024;
    const size_t OFF_VS = 8u * 1024 * 1024;
    const size_t OFF_KC = 12u * 1024 * 1024;
    const size_t OFF_VC = 16u * 1024 * 1024;

    char* ws = (char*)d_ws;
    const size_t MB = 1024 * 1024;
    bf16_t* wqkvTs = (bf16_t*)(ws + 0 * MB);   // [3072,1024]
    bf16_t* woTs   = (bf16_t*)(ws + 6 * MB);
    bf16_t* wqTc   = (bf16_t*)(ws + 8 * MB);
    bf16_t* wkvTc  = (bf16_t*)(ws + 10 * MB);  // [2048,1024]
    bf16_t* woTc   = (bf16_t*)(ws + 14 * MB);
    bf16_t* w1T    = (bf16_t*)(ws + 16 * MB);  // [4096,1024]
    bf16_t* w2T    = (bf16_t*)(ws + 24 * MB);  // [1024,4096]
    bf16_t* membf  = (bf16_t*)(ws + 32 * MB);  // [4096,1024]
    bf16_t* hbuf   = (bf16_t*)(ws + 40 * MB);  // [4096,1024]
    bf16_t* qbuf   = (bf16_t*)(ws + 48 * MB);  // [B,H,LT,HD]
    bf16_t* kbuf   = (bf16_t*)(ws + 56 * MB);  // [B,H,LS,HD]
    bf16_t* vbuf   = (bf16_t*)(ws + 64 * MB);  // [B,H,LS,HD]
    bf16_t* vTbuf  = (bf16_t*)(ws + 72 * MB);  // [B,H,HD,LS]
    bf16_t* Obuf   = (bf16_t*)(ws + 80 * MB);  // [B,LT,D]
    float*  attn_x  = (float*)(ws + 88 * MB);  // fp32 [4096,1024]
    float*  cross_x = (float*)(ws + 112 * MB); // fp32 [4096,1024]
    // FFN-phase overlays (attention buffers dead by then):
    bf16_t* ffnmid  = (bf16_t*)(ws + 48 * MB); // [4096,4096] bf16, 48..80
    float*  part    = (float*)(ws + 80 * MB);  // 2x fp32 [4096,1024], 80..112

    dim3 tb(32, 8);
    transpose_f2bf<<<dim3(32, 32), tb, 0, stream>>>(wq_s, wqkvTs, DM, DM);
    transpose_f2bf<<<dim3(32, 32), tb, 0, stream>>>(wk_s, wqkvTs + 1024 * 1024, DM, DM);
    transpose_f2bf<<<dim3(32, 32), tb, 0, stream>>>(wv_s, wqkvTs + 2 * 1024 * 1024, DM, DM);
    transpose_f2bf<<<dim3(32, 32), tb, 0, stream>>>(wo_s, woTs, DM, DM);
    transpose_f2bf<<<dim3(32, 32), tb, 0, stream>>>(wq_c, wqTc, DM, DM);
    transpose_f2bf<<<dim3(32, 32), tb, 0, stream>>>(wk_c, wkvTc, DM, DM);
    transpose_f2bf<<<dim3(32, 32), tb, 0, stream>>>(wv_c, wkvTc + 1024 * 1024, DM, DM);
    transpose_f2bf<<<dim3(32, 32), tb, 0, stream>>>(wo_c, woTc, DM, DM);
    transpose_f2bf<<<dim3(128, 32), tb, 0, stream>>>(w1, w1T, DM, FF);
    transpose_f2bf<<<dim3(32, 128), tb, 0, stream>>>(w2, w2T, FF, DM);

    f2bf_kernel<<<4096, 256, 0, stream>>>(mem, membf, (size_t)BB * LS * DM);

    // ---- self-attention block ----
    rmsnorm_kernel<<<BB * LT, 256, 0, stream>>>(x, g_sa, hbuf);
    gemm_qkv<<<dim3(32, 24), 256, 0, stream>>>(
        hbuf, wqkvTs, 24, hbuf, wqkvTs, 0,
        qbuf, out + OFF_KS, kbuf, out + OFF_VS, vbuf);
    transpose_bf<<<dim3(32, 2, 64), tb, 0, stream>>>(vbuf, vTbuf);
    flash_attn<true><<<dim3(16, 64), 256, 0, stream>>>(qbuf, kbuf, vTbuf, nullptr, Obuf);
    gemm_bt<EP_RES, 1><<<dim3(32, 8), 256, 0, stream>>>(
        Obuf, woTs, 1024, 1024, attn_x, x, nullptr);

    // ---- cross-attention block ----
    rmsnorm_kernel<<<BB * LT, 256, 0, stream>>>(attn_x, g_ca, hbuf);
    gemm_qkv<<<dim3(32, 24), 256, 0, stream>>>(
        hbuf, wqTc, 8, membf, wkvTc, 1,
        qbuf, out + OFF_KC, kbuf, out + OFF_VC, vbuf);
    transpose_bf<<<dim3(32, 2, 64), tb, 0, stream>>>(vbuf, vTbuf);
    flash_attn<false><<<dim3(16, 64), 256, 0, stream>>>(qbuf, kbuf, vTbuf, pemb, Obuf);
    gemm_bt<EP_RES, 1><<<dim3(32, 8), 256, 0, stream>>>(
        Obuf, woTc, 1024, 1024, cross_x, attn_x, nullptr);

    // ---- FFN block ----
    rmsnorm_kernel<<<BB * LT, 256, 0, stream>>>(cross_x, g_m, hbuf);
    gemm_bt<EP_RELU, 1><<<dim3(32, 32), 256, 0, stream>>>(
        hbuf, w1T, 4096, 1024, nullptr, nullptr, ffnmid);
    gemm_bt<EP_PART, 2><<<dim3(32, 8, 2), 256, 0, stream>>>(
        ffnmid, w2T, 1024, 4096, part, nullptr, nullptr);
    reduce2_res<<<4096, 256, 0, stream>>>(part, cross_x, out);
}